// Round 6
// baseline (3234.418 us; speedup 1.0000x reference)
//
#include <hip/hip_runtime.h>
#include <hip/hip_fp16.h>

#define TPB 256
#define SCB 256
#define SCI 16   // scan items per thread -> 4096 per block

typedef unsigned short ushort_t;

__device__ __forceinline__ float wred_max(float v) {
    #pragma unroll
    for (int o = 32; o >= 1; o >>= 1) v = fmaxf(v, __shfl_xor(v, o));
    return v;
}
__device__ __forceinline__ float wred_sum(float v) {
    #pragma unroll
    for (int o = 32; o >= 1; o >>= 1) v += __shfl_xor(v, o);
    return v;
}
__device__ __forceinline__ float h2f_u16(ushort_t u) {
    __half_raw r; r.x = u; return __half2float(__half(r));
}
__device__ __forceinline__ float h2f_lo(unsigned u) { return h2f_u16((ushort_t)(u & 0xffffu)); }
__device__ __forceinline__ float h2f_hi(unsigned u) { return h2f_u16((ushort_t)(u >> 16)); }
__device__ __forceinline__ unsigned f2h_pack(float a, float b) {
    __half ha = __float2half(a), hb = __float2half(b);
    __half_raw ra = *(__half_raw*)&ha, rb = *(__half_raw*)&hb;
    return (unsigned)ra.x | ((unsigned)rb.x << 16);
}

// ---------------- node featurizer: argmax-embed + 17->24 affine ----------------
__global__ void k_node(const float* __restrict__ x, const float* __restrict__ emb,
                       const float* __restrict__ nw, const float* __restrict__ nb,
                       float* __restrict__ h, int N, int XW, int NA) {
    __shared__ float s_w[24 * 17];
    __shared__ float s_b[24];
    for (int t = threadIdx.x; t < 24 * 17; t += blockDim.x) s_w[t] = nw[t];
    for (int t = threadIdx.x; t < 24; t += blockDim.x) s_b[t] = nb[t];
    __syncthreads();
    int n = blockIdx.x * blockDim.x + threadIdx.x;
    if (n >= N) return;
    const float* row = x + (size_t)n * XW;
    float best = row[0]; int bi = 0;
    for (int i = 1; i < NA; ++i) { float v = row[i]; if (v > best) { best = v; bi = i; } }
    float f[17];
    const float* er = emb + bi * 16;
    #pragma unroll
    for (int j = 0; j < 16; ++j) f[j] = er[j];
    f[16] = row[XW - 1];
    float* hr = h + (size_t)n * 24;
    #pragma unroll
    for (int k = 0; k < 24; ++k) {
        float a = s_b[k];
        #pragma unroll
        for (int j = 0; j < 17; ++j) a = fmaf(s_w[k * 17 + j], f[j], a);
        hr[k] = a;
    }
}

// ---------------- CSR build ----------------
__global__ void k_count(const int* __restrict__ ei, int* __restrict__ indeg, int E2) {
    int e = blockIdx.x * blockDim.x + threadIdx.x;
    if (e >= E2) return;
    atomicAdd(&indeg[ei[E2 + e]], 1);
}

__global__ void k_scan_bsum(const int* __restrict__ indeg, int* __restrict__ bsum, int N) {
    int base = blockIdx.x * SCB * SCI;
    int t = threadIdx.x;
    int s = 0;
    #pragma unroll
    for (int i = 0; i < SCI; ++i) {
        int idx = base + t * SCI + i;
        if (idx < N) s += indeg[idx];
    }
    #pragma unroll
    for (int o = 32; o >= 1; o >>= 1) s += __shfl_xor(s, o);
    __shared__ int red[SCB / 64];
    if ((t & 63) == 0) red[t >> 6] = s;
    __syncthreads();
    if (t == 0) {
        int tot = 0;
        for (int w = 0; w < SCB / 64; ++w) tot += red[w];
        bsum[blockIdx.x] = tot;
    }
}

__global__ void k_scan_final(const int* __restrict__ indeg, const int* __restrict__ bsum,
                             int* __restrict__ rowptr, int N, int nb) {
    __shared__ int s_t[SCB];
    __shared__ int s_boff;
    int base = blockIdx.x * SCB * SCI;
    int t = threadIdx.x;
    if (t == 0) {
        int off = 0;
        for (int i = 0; i < (int)blockIdx.x; ++i) off += bsum[i];
        s_boff = off;
        if (blockIdx.x == 0) {
            int tot = 0;
            for (int i = 0; i < nb; ++i) tot += bsum[i];
            rowptr[N] = tot;
        }
    }
    int loc[SCI]; int s = 0;
    #pragma unroll
    for (int i = 0; i < SCI; ++i) {
        int idx = base + t * SCI + i;
        int v = (idx < N) ? indeg[idx] : 0;
        loc[i] = s; s += v;
    }
    s_t[t] = s;
    __syncthreads();
    for (int o = 1; o < SCB; o <<= 1) {
        int v = (t >= o) ? s_t[t - o] : 0;
        __syncthreads();
        s_t[t] += v;
        __syncthreads();
    }
    int toff = ((t > 0) ? s_t[t - 1] : 0) + s_boff;
    #pragma unroll
    for (int i = 0; i < SCI; ++i) {
        int idx = base + t * SCI + i;
        if (idx < N) rowptr[idx] = toff + loc[i];
    }
}

__global__ void k_cursor(const int* __restrict__ rowptr, int* __restrict__ cursor, int N) {
    int n = blockIdx.x * blockDim.x + threadIdx.x;
    if (n < N) cursor[n] = rowptr[n];
}

// scatter edges into CSR; duplicate edge attr as fp16x4 in CSR order when dup16
__global__ void k_scatter(const int* __restrict__ ei, int* __restrict__ cursor,
                          int* __restrict__ csr_src, int* __restrict__ csr_aid,
                          uint2* __restrict__ att16, const float* __restrict__ attr,
                          int E2, int EU, int dup16) {
    int e = blockIdx.x * blockDim.x + threadIdx.x;
    if (e >= E2) return;
    int s = ei[e];
    int d = ei[E2 + e];
    int pos = atomicAdd(&cursor[d], 1);
    csr_src[pos] = s;
    int aid = (e < EU) ? e : e - EU;
    if (dup16) {
        float4 av = *(const float4*)(attr + (size_t)aid * 4);
        att16[pos] = make_uint2(f2h_pack(av.x, av.y), f2h_pack(av.z, av.w));
    } else {
        csr_aid[pos] = aid;
    }
}

// ---------------- per-node transforms: xl -> packed fp16, xr -> fp32 ----------------
template <int IN, int OUT, int GXS>
__global__ void k_xform(const float* __restrict__ h,
                        const float* __restrict__ wl, const float* __restrict__ bl,
                        const float* __restrict__ wr, const float* __restrict__ br,
                        ushort_t* __restrict__ xl, float* __restrict__ xr, int N) {
    __shared__ float s_wl[OUT * IN], s_wr[OUT * IN], s_bl[OUT], s_br[OUT];
    for (int t = threadIdx.x; t < OUT * IN; t += blockDim.x) { s_wl[t] = wl[t]; s_wr[t] = wr[t]; }
    for (int t = threadIdx.x; t < OUT; t += blockDim.x) { s_bl[t] = bl[t]; s_br[t] = br[t]; }
    __syncthreads();
    int n = blockIdx.x * blockDim.x + threadIdx.x;
    if (n >= N) return;
    float f[IN];
    const float* hr = h + (size_t)n * IN;
    #pragma unroll
    for (int j = 0; j < IN; ++j) f[j] = hr[j];
    unsigned* xo = (unsigned*)(xl + (size_t)n * GXS);
    #pragma unroll
    for (int q = 0; q < OUT / 2; ++q) {
        float a0 = s_bl[2 * q], a1 = s_bl[2 * q + 1];
        #pragma unroll
        for (int j = 0; j < IN; ++j) {
            a0 = fmaf(s_wl[(2 * q) * IN + j], f[j], a0);
            a1 = fmaf(s_wl[(2 * q + 1) * IN + j], f[j], a1);
        }
        xo[q] = f2h_pack(a0, a1);
    }
    float* xrr = xr + (size_t)n * OUT;
    #pragma unroll
    for (int k = 0; k < OUT; ++k) {
        float ar = s_br[k];
        #pragma unroll
        for (int j = 0; j < IN; ++j) ar = fmaf(s_wr[k * IN + j], f[j], ar);
        xrr[k] = ar;
    }
}

// ---------------- fused GATv2: one wave per node, fp16 gathers ----------------
// Phase A (lanes = edges): gather packed-fp16 xl[src] row (<=2 cachelines) -> LDS
// (pair-major words, stride 65, conflict-free) + logit inline; attr read coalesced
// from CSR-ordered fp16 duplicate (or gathered via aid fallback). Online softmax via
// wave reductions; p broadcast via per-wave LDS (all-lane write, convergent).
// Phase B (lanes = channels): dual-accumulator FMA over staged packed rows.
// Self-loop folded at the end.
template <int OUT, int GXS, int MINW>
__launch_bounds__(256, MINW)
__global__ void k_gat(const int* __restrict__ rowptr, const int* __restrict__ csr_src,
                      const int* __restrict__ csr_aid, const uint2* __restrict__ att16,
                      const float* __restrict__ attr,
                      const ushort_t* __restrict__ xl16, const float* __restrict__ xr,
                      const float* __restrict__ we, const float* __restrict__ ew,
                      const float* __restrict__ eb, const float* __restrict__ att,
                      const float* __restrict__ bias, float* __restrict__ h, int N) {
    constexpr int Q = OUT / 2;        // packed words per row
    constexpr int NW4 = GXS / 8;      // uint4 loads per row (3 for 24, 5 for 40)
    __shared__ float sC[OUT * 4], sCb[OUT], sAtt[OUT], sB[OUT];
    __shared__ float sXB[4][OUT];          // xr row + sCb, per wave
    __shared__ unsigned sXL[4][Q * 65];    // staged packed rows, word-major, stride 65
    __shared__ float sP[4][64];            // per-wave p broadcast
    // fold edge MLP into GAT edge projection: C = we @ edge_w (OUT x 4), cb = we @ edge_b
    for (int t = threadIdx.x; t < OUT * 5; t += blockDim.x) {
        int k = t / 5, c = t - k * 5;
        float a = 0.f;
        if (c < 4) { for (int j = 0; j < 12; ++j) a += we[k * 12 + j] * ew[j * 4 + c]; sC[k * 4 + c] = a; }
        else       { for (int j = 0; j < 12; ++j) a += we[k * 12 + j] * eb[j];          sCb[k] = a; }
    }
    for (int t = threadIdx.x; t < OUT; t += blockDim.x) { sAtt[t] = att[t]; sB[t] = bias[t]; }
    __syncthreads();

    int wid = threadIdx.x >> 6, lane = threadIdx.x & 63;
    int n = blockIdx.x * 4 + wid;
    if (n >= N) return;   // wave-uniform; no syncthreads after this point

    if (lane < OUT) sXB[wid][lane] = xr[(size_t)n * OUT + lane] + sCb[lane];

    unsigned* myXL = &sXL[wid][0];
    float* myP = &sP[wid][0];
    int rb = rowptr[n], re = rowptr[n + 1];

    float m = -INFINITY, den = 0.f, acc = 0.f;
    float as0 = 0.f, as1 = 0.f, as2 = 0.f, as3 = 0.f;   // raw-attr sums for self-loop mean

    for (int c0 = rb; c0 < re; c0 += 64) {
        int j = c0 + lane;
        float lg = -INFINITY;
        if (j < re) {
            int s = csr_src[j];
            float ax, ay, az, aw;
            if (att16) {
                uint2 au = att16[j];
                ax = h2f_lo(au.x); ay = h2f_hi(au.x); az = h2f_lo(au.y); aw = h2f_hi(au.y);
            } else {
                int aid = csr_aid[j];
                float4 av = *(const float4*)(attr + (size_t)aid * 4);
                ax = av.x; ay = av.y; az = av.z; aw = av.w;
            }
            as0 += ax; as1 += ay; as2 += az; as3 += aw;
            const uint4* xs4 = (const uint4*)(xl16 + (size_t)s * GXS);
            unsigned w[NW4 * 4];
            #pragma unroll
            for (int i = 0; i < NW4; ++i) {
                uint4 v = xs4[i];
                w[4 * i + 0] = v.x; w[4 * i + 1] = v.y; w[4 * i + 2] = v.z; w[4 * i + 3] = v.w;
            }
            lg = 0.f;
            #pragma unroll
            for (int q = 0; q < Q; ++q) {
                unsigned u = w[q];
                myXL[q * 65 + lane] = u;
                float f0 = h2f_lo(u), f1 = h2f_hi(u);
                int k0 = 2 * q, k1 = 2 * q + 1;
                float c0v = sXB[wid][k0];
                c0v = fmaf(sC[k0 * 4 + 0], ax, c0v);
                c0v = fmaf(sC[k0 * 4 + 1], ay, c0v);
                c0v = fmaf(sC[k0 * 4 + 2], az, c0v);
                c0v = fmaf(sC[k0 * 4 + 3], aw, c0v);
                float m0 = f0 + c0v;
                float lr0 = (m0 > 0.f) ? m0 : 0.2f * m0;
                lg = fmaf(sAtt[k0], lr0, lg);
                float c1v = sXB[wid][k1];
                c1v = fmaf(sC[k1 * 4 + 0], ax, c1v);
                c1v = fmaf(sC[k1 * 4 + 1], ay, c1v);
                c1v = fmaf(sC[k1 * 4 + 2], az, c1v);
                c1v = fmaf(sC[k1 * 4 + 3], aw, c1v);
                float m1 = f1 + c1v;
                float lr1 = (m1 > 0.f) ? m1 : 0.2f * m1;
                lg = fmaf(sAtt[k1], lr1, lg);
            }
        }
        float cm = wred_max(lg);
        float nm = fmaxf(m, cm);
        float sc = __expf(m - nm);          // m=-inf on first chunk -> 0
        float p = (j < re) ? __expf(lg - nm) : 0.f;
        myP[lane] = p;                      // ALL 64 lanes write (convergent)
        float ps = wred_sum(p);
        den = den * sc + ps;
        m = nm;
        int cnt = min(64, re - c0);
        if (lane < OUT) {
            const int qq = lane >> 1;
            const int sh = (lane & 1) << 4;
            float a0 = 0.f, a1 = 0.f;
            int t = 0;
            for (; t + 1 < cnt; t += 2) {
                unsigned u0 = myXL[qq * 65 + t];
                unsigned u1 = myXL[qq * 65 + t + 1];
                a0 = fmaf(myP[t],     h2f_u16((ushort_t)(u0 >> sh)), a0);
                a1 = fmaf(myP[t + 1], h2f_u16((ushort_t)(u1 >> sh)), a1);
            }
            if (t < cnt) {
                unsigned u0 = myXL[qq * 65 + t];
                a0 = fmaf(myP[t], h2f_u16((ushort_t)(u0 >> sh)), a0);
            }
            acc = fmaf(acc, sc, a0 + a1);
        }
    }

    // self-loop: attr = mean of incoming TRANSFORMED attrs (exact-0 if indeg==0)
    as0 = wred_sum(as0); as1 = wred_sum(as1); as2 = wred_sum(as2); as3 = wred_sum(as3);
    int cnt = re - rb;
    float inv = (cnt > 0) ? 1.f / (float)cnt : 0.f;
    float a0 = as0 * inv, a1 = as1 * inv, a2 = as2 * inv, a3 = as3 * inv;

    float xln = 0.f, contrib = 0.f;
    if (lane < OUT) {
        xln = h2f_u16(xl16[(size_t)n * GXS + lane]);
        float dot = 0.f;
        dot = fmaf(sC[lane * 4 + 0], a0, dot);
        dot = fmaf(sC[lane * 4 + 1], a1, dot);
        dot = fmaf(sC[lane * 4 + 2], a2, dot);
        dot = fmaf(sC[lane * 4 + 3], a3, dot);
        // sXB = xr + sCb; when indeg==0 the transformed self attr is 0 -> remove sCb
        float mm = xln + sXB[wid][lane] + ((cnt > 0) ? dot : -sCb[lane]);
        float lr = (mm > 0.f) ? mm : 0.2f * mm;
        contrib = sAtt[lane] * lr;
    }
    float lgs = wred_sum(contrib);
    float nm = fmaxf(m, lgs);
    float sc = __expf(m - nm);
    float p = __expf(lgs - nm);
    den = den * sc + p;                      // den >= p > 0: no div-by-zero
    if (lane < OUT) {
        acc = acc * sc + p * xln;
        float v = acc / den + sB[lane];
        h[(size_t)n * OUT + lane] = (v > 0.f) ? v : 0.f;
    }
}

// ---------------- mean pool: one block per graph, batch is sorted ----------------
__global__ void k_pool(const float* __restrict__ h, const int* __restrict__ batch,
                       float* __restrict__ pmean, int N) {
    int g = blockIdx.x;
    int a = 0, b = N;
    while (a < b) { int mid = (a + b) >> 1; if (batch[mid] < g) a = mid + 1; else b = mid; }
    int lo = a;
    a = lo; b = N;
    while (a < b) { int mid = (a + b) >> 1; if (batch[mid] < g + 1) a = mid + 1; else b = mid; }
    int hi = a;
    int cnt = hi - lo;
    int wid = threadIdx.x >> 6, lane = threadIdx.x & 63;
    float acc = 0.f;
    if (lane < 36) {
        for (int n = lo + wid; n < hi; n += 4) acc += h[(size_t)n * 36 + lane];
    }
    __shared__ float s_acc[4][36];
    if (lane < 36) s_acc[wid][lane] = acc;
    __syncthreads();
    if (threadIdx.x < 36) {
        float v = s_acc[0][threadIdx.x] + s_acc[1][threadIdx.x] +
                  s_acc[2][threadIdx.x] + s_acc[3][threadIdx.x];
        float iv = (cnt > 0) ? 1.f / (float)cnt : 0.f;
        pmean[(size_t)g * 36 + threadIdx.x] = v * iv;
    }
}

// ---------------- final head ----------------
__global__ void k_final(const float* __restrict__ pmean,
                        const float* __restrict__ fw, const float* __restrict__ fb,
                        float* __restrict__ out, int G) {
    int t = blockIdx.x * blockDim.x + threadIdx.x;
    if (t >= G * 64) return;
    int g = t / 64, o = t - g * 64;
    float a = fb[o];
    #pragma unroll
    for (int k = 0; k < 36; ++k) a = fmaf(pmean[(size_t)g * 36 + k], fw[o * 36 + k], a);
    out[t] = a;
}

extern "C" void kernel_launch(void* const* d_in, const int* in_sizes, int n_in,
                              void* d_out, int out_size, void* d_ws, size_t ws_size,
                              hipStream_t stream) {
    const float* x      = (const float*)d_in[0];
    const int*   ei     = (const int*)d_in[1];
    const float* eattr  = (const float*)d_in[2];
    const int*   batch  = (const int*)d_in[3];
    const float* emb    = (const float*)d_in[4];
    const float* node_w = (const float*)d_in[5];
    const float* node_b = (const float*)d_in[6];
    const float* edge_w = (const float*)d_in[7];
    const float* edge_b = (const float*)d_in[8];
    const float* c1_wl  = (const float*)d_in[9];
    const float* c1_bl  = (const float*)d_in[10];
    const float* c1_wr  = (const float*)d_in[11];
    const float* c1_br  = (const float*)d_in[12];
    const float* c1_we  = (const float*)d_in[13];
    const float* c1_att = (const float*)d_in[14];
    const float* c1_bias= (const float*)d_in[15];
    const float* c2_wl  = (const float*)d_in[16];
    const float* c2_bl  = (const float*)d_in[17];
    const float* c2_wr  = (const float*)d_in[18];
    const float* c2_br  = (const float*)d_in[19];
    const float* c2_we  = (const float*)d_in[20];
    const float* c2_att = (const float*)d_in[21];
    const float* c2_bias= (const float*)d_in[22];
    const float* fin_w  = (const float*)d_in[23];
    const float* fin_b  = (const float*)d_in[24];
    float* out = (float*)d_out;

    const int N  = in_sizes[3];
    const int E2 = in_sizes[1] / 2;
    const int EU = in_sizes[2] / 4;
    const int XW = in_sizes[0] / N;
    const int NA = in_sizes[4] / 16;
    const int G  = out_size / 64;

    // workspace layout (4B units)
    float* ws = (float*)d_ws;
    size_t off = 0;
    float*    h      = ws + off;               off += (size_t)N * 36;
    ushort_t* xl16   = (ushort_t*)(ws + off);  off += (size_t)N * 20;   // 40 halves max
    float*    xr     = ws + off;               off += (size_t)N * 36;
    float*    pmean  = ws + off;               off += (size_t)G * 36;
    int*      rowptr = (int*)(ws + off);       off += (size_t)N + 1;
    int*      cursor = (int*)(ws + off);       off += (size_t)N;
    int*      csr_src= (int*)(ws + off);       off += (size_t)E2;
    int*      csr_aid= (int*)(ws + off);       off += (size_t)E2;
    int*      bsum   = (int*)(ws + off);       off += 64;
    size_t need_base = off * 4;
    off = (off + 1) & ~(size_t)1;              // 8B align for uint2
    uint2*    att16  = (uint2*)(ws + off);     off += (size_t)E2 * 2;
    size_t need_full = off * 4;

    if (ws_size < need_base) return;  // loud failure: output stays poisoned
    const int use16 = (ws_size >= need_full) ? 1 : 0;
    uint2* att16_k = use16 ? att16 : (uint2*)nullptr;

    hipMemsetAsync(cursor, 0, (size_t)N * 4, stream);

    dim3 b(TPB);
    dim3 gN((N + TPB - 1) / TPB);
    dim3 gE((E2 + TPB - 1) / TPB);
    int nb = (N + SCB * SCI - 1) / (SCB * SCI);

    k_node<<<gN, b, 0, stream>>>(x, emb, node_w, node_b, h, N, XW, NA);
    k_count<<<gE, b, 0, stream>>>(ei, cursor, E2);
    k_scan_bsum<<<nb, SCB, 0, stream>>>(cursor, bsum, N);
    k_scan_final<<<nb, SCB, 0, stream>>>(cursor, bsum, rowptr, N, nb);
    k_cursor<<<gN, b, 0, stream>>>(rowptr, cursor, N);
    k_scatter<<<gE, b, 0, stream>>>(ei, cursor, csr_src, csr_aid, att16, eattr, E2, EU, use16);

    dim3 gW((N + 3) / 4);   // 4 waves per block, 1 wave per node

    // ---- layer 1 (24 -> 24): GXS=24 halves; ~14KB LDS -> 8 blocks/CU (wave cap) ----
    k_xform<24, 24, 24><<<gN, b, 0, stream>>>(h, c1_wl, c1_bl, c1_wr, c1_br, xl16, xr, N);
    k_gat<24, 24, 8><<<gW, b, 0, stream>>>(rowptr, csr_src, csr_aid, att16_k, eattr, xl16, xr,
                                           c1_we, edge_w, edge_b, c1_att, c1_bias, h, N);

    // ---- layer 2 (24 -> 36): GXS=40 halves; ~21KB LDS -> 6-7 blocks/CU ----
    k_xform<24, 36, 40><<<gN, b, 0, stream>>>(h, c2_wl, c2_bl, c2_wr, c2_br, xl16, xr, N);
    k_gat<36, 40, 6><<<gW, b, 0, stream>>>(rowptr, csr_src, csr_aid, att16_k, eattr, xl16, xr,
                                           c2_we, edge_w, edge_b, c2_att, c2_bias, h, N);

    // ---- pool + head ----
    k_pool<<<G, b, 0, stream>>>(h, batch, pmean, N);
    k_final<<<(G * 64 + TPB - 1) / TPB, b, 0, stream>>>(pmean, fin_w, fin_b, out, G);
}

// Round 7
// 2578.364 us; speedup vs baseline: 1.2544x; 1.2544x over previous
//
#include <hip/hip_runtime.h>
#include <hip/hip_fp16.h>

#define TPB 256
#define SCB 256
#define SCI 16   // scan items per thread -> 4096 per block

__device__ __forceinline__ float wred_max(float v) {
    #pragma unroll
    for (int o = 32; o >= 1; o >>= 1) v = fmaxf(v, __shfl_xor(v, o));
    return v;
}
__device__ __forceinline__ float wred_sum(float v) {
    #pragma unroll
    for (int o = 32; o >= 1; o >>= 1) v += __shfl_xor(v, o);
    return v;
}
__device__ __forceinline__ float h2f_u16(unsigned short u) {
    __half_raw r; r.x = u; return __half2float(__half(r));
}
__device__ __forceinline__ float h2f_lo(unsigned u) { return h2f_u16((unsigned short)(u & 0xffffu)); }
__device__ __forceinline__ float h2f_hi(unsigned u) { return h2f_u16((unsigned short)(u >> 16)); }
__device__ __forceinline__ unsigned f2h_pack(float a, float b) {
    __half ha = __float2half(a), hb = __float2half(b);
    __half_raw ra = *(__half_raw*)&ha, rb = *(__half_raw*)&hb;
    return (unsigned)ra.x | ((unsigned)rb.x << 16);
}

// ---------------- node featurizer: argmax-embed + 17->24 affine ----------------
__global__ void k_node(const float* __restrict__ x, const float* __restrict__ emb,
                       const float* __restrict__ nw, const float* __restrict__ nb,
                       float* __restrict__ h, int N, int XW, int NA) {
    __shared__ float s_w[24 * 17];
    __shared__ float s_b[24];
    for (int t = threadIdx.x; t < 24 * 17; t += blockDim.x) s_w[t] = nw[t];
    for (int t = threadIdx.x; t < 24; t += blockDim.x) s_b[t] = nb[t];
    __syncthreads();
    int n = blockIdx.x * blockDim.x + threadIdx.x;
    if (n >= N) return;
    const float* row = x + (size_t)n * XW;
    float best = row[0]; int bi = 0;
    for (int i = 1; i < NA; ++i) { float v = row[i]; if (v > best) { best = v; bi = i; } }
    float f[17];
    const float* er = emb + bi * 16;
    #pragma unroll
    for (int j = 0; j < 16; ++j) f[j] = er[j];
    f[16] = row[XW - 1];
    float* hr = h + (size_t)n * 24;
    #pragma unroll
    for (int k = 0; k < 24; ++k) {
        float a = s_b[k];
        #pragma unroll
        for (int j = 0; j < 17; ++j) a = fmaf(s_w[k * 17 + j], f[j], a);
        hr[k] = a;
    }
}

// ---------------- CSR build ----------------
__global__ void k_count(const int* __restrict__ ei, int* __restrict__ indeg, int E2) {
    int e = blockIdx.x * blockDim.x + threadIdx.x;
    if (e >= E2) return;
    atomicAdd(&indeg[ei[E2 + e]], 1);
}

__global__ void k_scan_bsum(const int* __restrict__ indeg, int* __restrict__ bsum, int N) {
    int base = blockIdx.x * SCB * SCI;
    int t = threadIdx.x;
    int s = 0;
    #pragma unroll
    for (int i = 0; i < SCI; ++i) {
        int idx = base + t * SCI + i;
        if (idx < N) s += indeg[idx];
    }
    #pragma unroll
    for (int o = 32; o >= 1; o >>= 1) s += __shfl_xor(s, o);
    __shared__ int red[SCB / 64];
    if ((t & 63) == 0) red[t >> 6] = s;
    __syncthreads();
    if (t == 0) {
        int tot = 0;
        for (int w = 0; w < SCB / 64; ++w) tot += red[w];
        bsum[blockIdx.x] = tot;
    }
}

__global__ void k_scan_final(const int* __restrict__ indeg, const int* __restrict__ bsum,
                             int* __restrict__ rowptr, int N, int nb) {
    __shared__ int s_t[SCB];
    __shared__ int s_boff;
    int base = blockIdx.x * SCB * SCI;
    int t = threadIdx.x;
    if (t == 0) {
        int off = 0;
        for (int i = 0; i < (int)blockIdx.x; ++i) off += bsum[i];
        s_boff = off;
        if (blockIdx.x == 0) {
            int tot = 0;
            for (int i = 0; i < nb; ++i) tot += bsum[i];
            rowptr[N] = tot;
        }
    }
    int loc[SCI]; int s = 0;
    #pragma unroll
    for (int i = 0; i < SCI; ++i) {
        int idx = base + t * SCI + i;
        int v = (idx < N) ? indeg[idx] : 0;
        loc[i] = s; s += v;
    }
    s_t[t] = s;
    __syncthreads();
    for (int o = 1; o < SCB; o <<= 1) {
        int v = (t >= o) ? s_t[t - o] : 0;
        __syncthreads();
        s_t[t] += v;
        __syncthreads();
    }
    int toff = ((t > 0) ? s_t[t - 1] : 0) + s_boff;
    #pragma unroll
    for (int i = 0; i < SCI; ++i) {
        int idx = base + t * SCI + i;
        if (idx < N) rowptr[idx] = toff + loc[i];
    }
}

__global__ void k_cursor(const int* __restrict__ rowptr, int* __restrict__ cursor, int N) {
    int n = blockIdx.x * blockDim.x + threadIdx.x;
    if (n < N) cursor[n] = rowptr[n];
}

__global__ void k_scatter(const int* __restrict__ ei, int* __restrict__ cursor,
                          int* __restrict__ csr_src, int* __restrict__ csr_aid,
                          int E2, int EU) {
    int e = blockIdx.x * blockDim.x + threadIdx.x;
    if (e >= E2) return;
    int s = ei[e];
    int d = ei[E2 + e];
    int pos = atomicAdd(&cursor[d], 1);
    csr_src[pos] = s;
    csr_aid[pos] = (e < EU) ? e : e - EU;
}

// duplicate edge attrs into CSR order as packed fp16 (coalesced write, one random read)
__global__ void k_attdup(const int* __restrict__ csr_aid, const float* __restrict__ attr,
                         uint2* __restrict__ att16, int E2) {
    int e = blockIdx.x * blockDim.x + threadIdx.x;
    if (e >= E2) return;
    float4 av = *(const float4*)(attr + (size_t)csr_aid[e] * 4);
    att16[e] = make_uint2(f2h_pack(av.x, av.y), f2h_pack(av.z, av.w));
}

// ---------------- per-node left/right transforms (both fp32) ----------------
template <int IN, int OUT>
__global__ void k_xform(const float* __restrict__ h,
                        const float* __restrict__ wl, const float* __restrict__ bl,
                        const float* __restrict__ wr, const float* __restrict__ br,
                        float* __restrict__ xl, float* __restrict__ xr, int N) {
    __shared__ float s_wl[OUT * IN], s_wr[OUT * IN], s_bl[OUT], s_br[OUT];
    for (int t = threadIdx.x; t < OUT * IN; t += blockDim.x) { s_wl[t] = wl[t]; s_wr[t] = wr[t]; }
    for (int t = threadIdx.x; t < OUT; t += blockDim.x) { s_bl[t] = bl[t]; s_br[t] = br[t]; }
    __syncthreads();
    int n = blockIdx.x * blockDim.x + threadIdx.x;
    if (n >= N) return;
    float f[IN];
    const float* hr = h + (size_t)n * IN;
    #pragma unroll
    for (int j = 0; j < IN; ++j) f[j] = hr[j];
    float* xlr = xl + (size_t)n * OUT;
    float* xrr = xr + (size_t)n * OUT;
    #pragma unroll
    for (int k = 0; k < OUT; ++k) {
        float al = s_bl[k], ar = s_br[k];
        #pragma unroll
        for (int j = 0; j < IN; ++j) {
            al = fmaf(s_wl[k * IN + j], f[j], al);
            ar = fmaf(s_wr[k * IN + j], f[j], ar);
        }
        xlr[k] = al; xrr[k] = ar;
    }
}

// ---------------- fused GATv2: one wave per node, fp32 xl, coalesced fp16 attr ----
// Phase A (lanes = edges): gather xl[src] row float4-wise -> LDS (channel-major,
// 65-dword stride, conflict-free) + logit inline; edge attr comes from the CSR-ordered
// fp16 duplicate (coalesced uint2) or aid-gather fallback. Online softmax via wave
// reductions; p broadcast via per-wave LDS (all-lane write while convergent).
// Phase B (lanes = channels): quad-accumulator FMA over staged rows. Self-loop folded.
template <int OUT, int MINW>
__launch_bounds__(256, MINW)
__global__ void k_gat(const int* __restrict__ rowptr, const int* __restrict__ csr_src,
                      const int* __restrict__ csr_aid, const uint2* __restrict__ att16,
                      const float* __restrict__ attr,
                      const float* __restrict__ xl, const float* __restrict__ xr,
                      const float* __restrict__ we, const float* __restrict__ ew,
                      const float* __restrict__ eb, const float* __restrict__ att,
                      const float* __restrict__ bias, float* __restrict__ h, int N) {
    __shared__ float sC[OUT * 4], sCb[OUT], sAtt[OUT], sB[OUT];
    __shared__ float sXB[4][OUT];        // xr row + sCb, per wave
    __shared__ float sXL[4][OUT * 65];   // staged rows, channel-major, stride 65 = conflict-free
    __shared__ float sP[4][64];          // per-wave p broadcast (all-lane write)
    // fold edge MLP into GAT edge projection: C = we @ edge_w (OUT x 4), cb = we @ edge_b
    for (int t = threadIdx.x; t < OUT * 5; t += blockDim.x) {
        int k = t / 5, c = t - k * 5;
        float a = 0.f;
        if (c < 4) { for (int j = 0; j < 12; ++j) a += we[k * 12 + j] * ew[j * 4 + c]; sC[k * 4 + c] = a; }
        else       { for (int j = 0; j < 12; ++j) a += we[k * 12 + j] * eb[j];          sCb[k] = a; }
    }
    for (int t = threadIdx.x; t < OUT; t += blockDim.x) { sAtt[t] = att[t]; sB[t] = bias[t]; }
    __syncthreads();

    int wid = threadIdx.x >> 6, lane = threadIdx.x & 63;
    int n = blockIdx.x * 4 + wid;
    if (n >= N) return;   // wave-uniform; no syncthreads after this point

    if (lane < OUT) sXB[wid][lane] = xr[(size_t)n * OUT + lane] + sCb[lane];

    float* myXL = &sXL[wid][0];
    float* myP  = &sP[wid][0];
    int rb = rowptr[n], re = rowptr[n + 1];

    float m = -INFINITY, den = 0.f, acc = 0.f;
    float as0 = 0.f, as1 = 0.f, as2 = 0.f, as3 = 0.f;   // raw-attr sums for self-loop mean

    for (int c0 = rb; c0 < re; c0 += 64) {
        int j = c0 + lane;
        float lg = -INFINITY;
        if (j < re) {
            int s = csr_src[j];
            float ax, ay, az, aw;
            if (att16) {
                uint2 au = att16[j];
                ax = h2f_lo(au.x); ay = h2f_hi(au.x); az = h2f_lo(au.y); aw = h2f_hi(au.y);
            } else {
                int aid = csr_aid[j];
                float4 av = *(const float4*)(attr + (size_t)aid * 4);
                ax = av.x; ay = av.y; az = av.z; aw = av.w;
            }
            as0 += ax; as1 += ay; as2 += az; as3 += aw;
            const float4* xs4 = (const float4*)(xl + (size_t)s * OUT);
            lg = 0.f;
            #pragma unroll
            for (int q4 = 0; q4 < OUT / 4; ++q4) {
                float4 v = xs4[q4];
                myXL[(4 * q4 + 0) * 65 + lane] = v.x;
                myXL[(4 * q4 + 1) * 65 + lane] = v.y;
                myXL[(4 * q4 + 2) * 65 + lane] = v.z;
                myXL[(4 * q4 + 3) * 65 + lane] = v.w;
                #pragma unroll
                for (int r = 0; r < 4; ++r) {
                    int k = 4 * q4 + r;
                    float xlv = (r == 0) ? v.x : (r == 1) ? v.y : (r == 2) ? v.z : v.w;
                    float c = sXB[wid][k];
                    c = fmaf(sC[k * 4 + 0], ax, c);
                    c = fmaf(sC[k * 4 + 1], ay, c);
                    c = fmaf(sC[k * 4 + 2], az, c);
                    c = fmaf(sC[k * 4 + 3], aw, c);
                    float mm = xlv + c;
                    float lr = (mm > 0.f) ? mm : 0.2f * mm;
                    lg = fmaf(sAtt[k], lr, lg);
                }
            }
        }
        float cm = wred_max(lg);
        float nm = fmaxf(m, cm);
        float sc = __expf(m - nm);          // m=-inf on first chunk -> 0
        float p = (j < re) ? __expf(lg - nm) : 0.f;
        myP[lane] = p;                      // ALL 64 lanes write (convergent)
        float ps = wred_sum(p);
        den = den * sc + ps;
        m = nm;
        int cnt = min(64, re - c0);
        if (lane < OUT) {
            float a0 = 0.f, a1 = 0.f, a2 = 0.f, a3 = 0.f;
            int t = 0;
            for (; t + 3 < cnt; t += 4) {
                a0 = fmaf(myP[t],     myXL[lane * 65 + t],     a0);
                a1 = fmaf(myP[t + 1], myXL[lane * 65 + t + 1], a1);
                a2 = fmaf(myP[t + 2], myXL[lane * 65 + t + 2], a2);
                a3 = fmaf(myP[t + 3], myXL[lane * 65 + t + 3], a3);
            }
            for (; t < cnt; ++t) a0 = fmaf(myP[t], myXL[lane * 65 + t], a0);
            acc = fmaf(acc, sc, (a0 + a1) + (a2 + a3));
        }
    }

    // self-loop: attr = mean of incoming TRANSFORMED attrs (exact-0 if indeg==0)
    as0 = wred_sum(as0); as1 = wred_sum(as1); as2 = wred_sum(as2); as3 = wred_sum(as3);
    int cnt = re - rb;
    float inv = (cnt > 0) ? 1.f / (float)cnt : 0.f;
    float a0 = as0 * inv, a1 = as1 * inv, a2 = as2 * inv, a3 = as3 * inv;

    float xln = 0.f, contrib = 0.f;
    if (lane < OUT) {
        xln = xl[(size_t)n * OUT + lane];
        float dot = 0.f;
        dot = fmaf(sC[lane * 4 + 0], a0, dot);
        dot = fmaf(sC[lane * 4 + 1], a1, dot);
        dot = fmaf(sC[lane * 4 + 2], a2, dot);
        dot = fmaf(sC[lane * 4 + 3], a3, dot);
        // sXB = xr + sCb; when indeg==0 the transformed self attr is 0 -> remove sCb
        float mm = xln + sXB[wid][lane] + ((cnt > 0) ? dot : -sCb[lane]);
        float lr = (mm > 0.f) ? mm : 0.2f * mm;
        contrib = sAtt[lane] * lr;
    }
    float lgs = wred_sum(contrib);
    float nm = fmaxf(m, lgs);
    float sc = __expf(m - nm);
    float p = __expf(lgs - nm);
    den = den * sc + p;                      // den >= p > 0: no div-by-zero
    if (lane < OUT) {
        acc = acc * sc + p * xln;
        float v = acc / den + sB[lane];
        h[(size_t)n * OUT + lane] = (v > 0.f) ? v : 0.f;
    }
}

// ---------------- mean pool: one block per graph, batch is sorted ----------------
__global__ void k_pool(const float* __restrict__ h, const int* __restrict__ batch,
                       float* __restrict__ pmean, int N) {
    int g = blockIdx.x;
    int a = 0, b = N;
    while (a < b) { int mid = (a + b) >> 1; if (batch[mid] < g) a = mid + 1; else b = mid; }
    int lo = a;
    a = lo; b = N;
    while (a < b) { int mid = (a + b) >> 1; if (batch[mid] < g + 1) a = mid + 1; else b = mid; }
    int hi = a;
    int cnt = hi - lo;
    int wid = threadIdx.x >> 6, lane = threadIdx.x & 63;
    float acc = 0.f;
    if (lane < 36) {
        for (int n = lo + wid; n < hi; n += 4) acc += h[(size_t)n * 36 + lane];
    }
    __shared__ float s_acc[4][36];
    if (lane < 36) s_acc[wid][lane] = acc;
    __syncthreads();
    if (threadIdx.x < 36) {
        float v = s_acc[0][threadIdx.x] + s_acc[1][threadIdx.x] +
                  s_acc[2][threadIdx.x] + s_acc[3][threadIdx.x];
        float iv = (cnt > 0) ? 1.f / (float)cnt : 0.f;
        pmean[(size_t)g * 36 + threadIdx.x] = v * iv;
    }
}

// ---------------- final head ----------------
__global__ void k_final(const float* __restrict__ pmean,
                        const float* __restrict__ fw, const float* __restrict__ fb,
                        float* __restrict__ out, int G) {
    int t = blockIdx.x * blockDim.x + threadIdx.x;
    if (t >= G * 64) return;
    int g = t / 64, o = t - g * 64;
    float a = fb[o];
    #pragma unroll
    for (int k = 0; k < 36; ++k) a = fmaf(pmean[(size_t)g * 36 + k], fw[o * 36 + k], a);
    out[t] = a;
}

extern "C" void kernel_launch(void* const* d_in, const int* in_sizes, int n_in,
                              void* d_out, int out_size, void* d_ws, size_t ws_size,
                              hipStream_t stream) {
    const float* x      = (const float*)d_in[0];
    const int*   ei     = (const int*)d_in[1];
    const float* eattr  = (const float*)d_in[2];
    const int*   batch  = (const int*)d_in[3];
    const float* emb    = (const float*)d_in[4];
    const float* node_w = (const float*)d_in[5];
    const float* node_b = (const float*)d_in[6];
    const float* edge_w = (const float*)d_in[7];
    const float* edge_b = (const float*)d_in[8];
    const float* c1_wl  = (const float*)d_in[9];
    const float* c1_bl  = (const float*)d_in[10];
    const float* c1_wr  = (const float*)d_in[11];
    const float* c1_br  = (const float*)d_in[12];
    const float* c1_we  = (const float*)d_in[13];
    const float* c1_att = (const float*)d_in[14];
    const float* c1_bias= (const float*)d_in[15];
    const float* c2_wl  = (const float*)d_in[16];
    const float* c2_bl  = (const float*)d_in[17];
    const float* c2_wr  = (const float*)d_in[18];
    const float* c2_br  = (const float*)d_in[19];
    const float* c2_we  = (const float*)d_in[20];
    const float* c2_att = (const float*)d_in[21];
    const float* c2_bias= (const float*)d_in[22];
    const float* fin_w  = (const float*)d_in[23];
    const float* fin_b  = (const float*)d_in[24];
    float* out = (float*)d_out;

    const int N  = in_sizes[3];
    const int E2 = in_sizes[1] / 2;
    const int EU = in_sizes[2] / 4;
    const int XW = in_sizes[0] / N;
    const int NA = in_sizes[4] / 16;
    const int G  = out_size / 64;

    // workspace layout (4B units); all segments 16B-aligned
    float* ws = (float*)d_ws;
    size_t off = 0;
    float*  h      = ws + off;              off += (size_t)N * 36;
    float*  xl     = ws + off;              off += (size_t)N * 36;
    float*  xr     = ws + off;              off += (size_t)N * 36;
    float*  pmean  = ws + off;              off += (size_t)G * 36;
    int*    rowptr = (int*)(ws + off);      off += (size_t)N + 1;
    int*    cursor = (int*)(ws + off);      off += (size_t)N;
    int*    csr_src= (int*)(ws + off);      off += (size_t)E2;
    int*    csr_aid= (int*)(ws + off);      off += (size_t)E2;
    int*    bsum   = (int*)(ws + off);      off += 64;
    size_t need_base = off * 4;
    off = (off + 1) & ~(size_t)1;           // 8B align for uint2
    uint2*  att16  = (uint2*)(ws + off);    off += (size_t)E2 * 2;
    size_t need_full = off * 4;

    if (ws_size < need_base) return;  // loud failure: output stays poisoned
    const int use16 = (ws_size >= need_full) ? 1 : 0;
    uint2* att16_k = use16 ? att16 : (uint2*)nullptr;

    hipMemsetAsync(cursor, 0, (size_t)N * 4, stream);

    dim3 b(TPB);
    dim3 gN((N + TPB - 1) / TPB);
    dim3 gE((E2 + TPB - 1) / TPB);
    int nb = (N + SCB * SCI - 1) / (SCB * SCI);

    k_node<<<gN, b, 0, stream>>>(x, emb, node_w, node_b, h, N, XW, NA);
    k_count<<<gE, b, 0, stream>>>(ei, cursor, E2);
    k_scan_bsum<<<nb, SCB, 0, stream>>>(cursor, bsum, N);
    k_scan_final<<<nb, SCB, 0, stream>>>(cursor, bsum, rowptr, N, nb);
    k_cursor<<<gN, b, 0, stream>>>(rowptr, cursor, N);
    k_scatter<<<gE, b, 0, stream>>>(ei, cursor, csr_src, csr_aid, E2, EU);
    if (use16) k_attdup<<<gE, b, 0, stream>>>(csr_aid, eattr, att16, E2);

    dim3 gW((N + 3) / 4);   // 4 waves per block, 1 wave per node

    // ---- layer 1 (24 -> 24): ~27.0KB LDS -> 6 blocks/CU ----
    k_xform<24, 24><<<gN, b, 0, stream>>>(h, c1_wl, c1_bl, c1_wr, c1_br, xl, xr, N);
    k_gat<24, 6><<<gW, b, 0, stream>>>(rowptr, csr_src, csr_aid, att16_k, eattr, xl, xr,
                                       c1_we, edge_w, edge_b, c1_att, c1_bias, h, N);

    // ---- layer 2 (24 -> 36): ~40.0KB LDS -> 4 blocks/CU ----
    k_xform<24, 36><<<gN, b, 0, stream>>>(h, c2_wl, c2_bl, c2_wr, c2_br, xl, xr, N);
    k_gat<36, 4><<<gW, b, 0, stream>>>(rowptr, csr_src, csr_aid, att16_k, eattr, xl, xr,
                                       c2_we, edge_w, edge_b, c2_att, c2_bias, h, N);

    // ---- pool + head ----
    k_pool<<<G, b, 0, stream>>>(h, batch, pmean, N);
    k_final<<<(G * 64 + TPB - 1) / TPB, b, 0, stream>>>(pmean, fin_w, fin_b, out, G);
}